// Round 1
// baseline (1599.550 us; speedup 1.0000x reference)
//
#include <hip/hip_runtime.h>
#include <hip/hip_bf16.h>
#include <math.h>

// Problem constants: V=96, D=128, T=64, H=8, HD=16, FF=512, L=4, B=4096
#define NTHR 512

typedef __attribute__((ext_vector_type(8))) short short8;
typedef __attribute__((ext_vector_type(4))) float f32x4;

#define MFMA(a, b, c) __builtin_amdgcn_mfma_f32_16x16x32_bf16((a), (b), (c), 0, 0, 0)

// ---- workspace layout (bf16 element offsets) ----
// weights pre-converted to bf16 and swizzled [K/8][N][8] for coalesced B-frag loads
#define WS_EMB 0                      // [96][128]  -> 12288
#define WS_WQ  12288                  // 4x[128][128]
#define WS_WK  (WS_WQ + 65536)
#define WS_WV  (WS_WK + 65536)
#define WS_WO  (WS_WV + 65536)
#define WS_W1  (WS_WO + 65536)        // 4x[512][128]
#define WS_W2  (WS_W1 + 262144)       // 4x[128][512]
#define WS_END (WS_W2 + 262144)       // 798720 bf16 elems = 1,597,440 B

__device__ __forceinline__ short f2bf(float f) {
  union { float f; unsigned u; } c; c.f = f;
  unsigned r = (c.u + 0x7FFFu + ((c.u >> 16) & 1u)) >> 16;   // RNE
  return (short)(unsigned short)r;
}

// Convert f32 weights to bf16, swizzled so that B-fragment loads
// (8 consecutive k at fixed n, lanes = consecutive n) are coalesced:
// dst[(k>>3)*N*8 + n*8 + (k&7)] = W[n][k]
__global__ void prep_weights(const float* __restrict__ tok_emb,
                             const float* __restrict__ Wq, const float* __restrict__ Wk,
                             const float* __restrict__ Wv, const float* __restrict__ Wo,
                             const float* __restrict__ W1, const float* __restrict__ W2,
                             short* __restrict__ wsb) {
  int i = blockIdx.x * NTHR + threadIdx.x;
  if (i < 12288) {                       // tok_emb [96][128]
    int n = i >> 7, k = i & 127;
    wsb[WS_EMB + (k >> 3) * 768 + n * 8 + (k & 7)] = f2bf(tok_emb[i]);
    return;
  }
  i -= 12288;
  if (i < 262144) {                      // Wq,Wk,Wv,Wo: 4 tensors x [4][128][128]
    int tensor = i >> 16;
    int rem = i & 65535;
    int l = rem >> 14;
    int w = rem & 16383;
    int n = w >> 7, k = w & 127;
    const float* src = tensor == 0 ? Wq : tensor == 1 ? Wk : tensor == 2 ? Wv : Wo;
    wsb[WS_WQ + tensor * 65536 + l * 16384 + (k >> 3) * 1024 + n * 8 + (k & 7)] =
        f2bf(src[rem]);
    return;
  }
  i -= 262144;
  if (i < 262144) {                      // W1 [4][512][128]
    int l = i >> 16;
    int w = i & 65535;
    int n = w >> 7, k = w & 127;
    wsb[WS_W1 + l * 65536 + (k >> 3) * 4096 + n * 8 + (k & 7)] = f2bf(W1[i]);
    return;
  }
  i -= 262144;
  if (i < 262144) {                      // W2 [4][128][512]
    int l = i >> 16;
    int w = i & 65535;
    int n = w >> 9, k = w & 511;
    wsb[WS_W2 + l * 65536 + (k >> 3) * 1024 + n * 8 + (k & 7)] = f2bf(W2[i]);
  }
}

// LN over sX (f32, stride 132) -> dst (bf16, stride 136). 8 threads/row.
__device__ __forceinline__ void layernorm(const float* __restrict__ sXl,
                                          short* __restrict__ dstl,
                                          const float* __restrict__ g,
                                          const float* __restrict__ be, int tid) {
  int r = tid >> 3, t8 = tid & 7;
  const float* row = sXl + r * 132 + t8 * 16;
  float s = 0.f, s2 = 0.f;
#pragma unroll
  for (int j = 0; j < 16; ++j) { float v = row[j]; s += v; s2 += v * v; }
#pragma unroll
  for (int m = 1; m < 8; m <<= 1) {
    s += __shfl_xor(s, m, 64);
    s2 += __shfl_xor(s2, m, 64);
  }
  float mean = s * 0.0078125f;
  float rs = rsqrtf(s2 * 0.0078125f - mean * mean + 1e-5f);
  short* dst = dstl + r * 136 + t8 * 16;
  const float* gp = g + t8 * 16;
  const float* bp = be + t8 * 16;
#pragma unroll
  for (int j = 0; j < 16; ++j) dst[j] = f2bf((row[j] - mean) * rs * gp[j] + bp[j]);
}

// One block per sequence. 8 waves, N-split over output tiles (each wave loops
// all 4 M-tiles so every weight byte is loaded once per block).
// MFMA 16x16x32 bf16 layouts (HW-verified, learn_hip m89/m91):
//   A-frag: A[lane&15][(lane>>4)*8 + i]
//   B-frag: B[(lane>>4)*8 + i][lane&15]
//   D:      row = (lane>>4)*4 + reg, col = lane&15
__global__ __launch_bounds__(512, 2)
void lm_forward(const int* __restrict__ idx, const int* __restrict__ targets,
                const float* __restrict__ tok_emb, const float* __restrict__ pos_emb,
                const float* __restrict__ bo, const float* __restrict__ ln1_g,
                const float* __restrict__ ln1_b, const float* __restrict__ ln2_g,
                const float* __restrict__ ln2_b, const float* __restrict__ b1,
                const float* __restrict__ b2, const float* __restrict__ lnf_g,
                const float* __restrict__ lnf_b, const float* __restrict__ lm_b,
                const short* __restrict__ wsb, float* __restrict__ out,
                float* __restrict__ loss_part) {
  __shared__ float sX[64 * 132];    // residual stream (f32)
  __shared__ float sS[64 * 132];    // scores (2 heads) / logits (f32)
  __shared__ short sXn[64 * 136];   // xn (bf16); reused as attention output
  __shared__ short sP[64 * 136];    // softmax P (2 heads) / FF hidden chunk
  __shared__ short sQ[64 * 136];    // Q (bf16)
  __shared__ short sK[64 * 136];    // K (bf16)
  __shared__ short sVT[128 * 72];   // V transposed [d][t] so PV B-frag is contiguous
  __shared__ float sRed[64];

  const int b = blockIdx.x;
  const int tid = threadIdx.x;
  const int wave = tid >> 6;
  const int lane = tid & 63;
  const int lr = lane & 15;
  const int lg = lane >> 4;
  const f32x4 fzero = {0.f, 0.f, 0.f, 0.f};
  const short8 szero = {0, 0, 0, 0, 0, 0, 0, 0};

  // ---- embedding: x = tok_emb[idx] + pos_emb ----
  for (int i = tid; i < 8192; i += NTHR) {
    int t = i >> 7, d = i & 127;
    sX[t * 132 + d] = tok_emb[idx[b * 64 + t] * 128 + d] + pos_emb[i];
  }
  __syncthreads();

#pragma unroll 1
  for (int l = 0; l < 4; ++l) {
    // ---- LN1 ----
    layernorm(sX, sXn, ln1_g + l * 128, ln1_b + l * 128, tid);
    __syncthreads();

    // ---- QKV GEMM: wave w computes q,k,v columns 16w..16w+15 ----
    {
      const short* wq = wsb + WS_WQ + l * 16384;
      const short* wk = wsb + WS_WK + l * 16384;
      const short* wv = wsb + WS_WV + l * 16384;
      f32x4 accq[4], acck[4], accv[4];
#pragma unroll
      for (int m = 0; m < 4; ++m) { accq[m] = fzero; acck[m] = fzero; accv[m] = fzero; }
#pragma unroll
      for (int ks = 0; ks < 4; ++ks) {
        short8 am[4];
#pragma unroll
        for (int m = 0; m < 4; ++m)
          am[m] = *(const short8*)(sXn + (m * 16 + lr) * 136 + ks * 32 + lg * 8);
        int boff = (ks * 4 + lg) * 1024 + (wave * 16 + lr) * 8;
        short8 bq = *(const short8*)(wq + boff);
        short8 bk = *(const short8*)(wk + boff);
        short8 bv = *(const short8*)(wv + boff);
#pragma unroll
        for (int m = 0; m < 4; ++m) {
          accq[m] = MFMA(am[m], bq, accq[m]);
          acck[m] = MFMA(am[m], bk, acck[m]);
          accv[m] = MFMA(am[m], bv, accv[m]);
        }
      }
      int col = wave * 16 + lr;
#pragma unroll
      for (int m = 0; m < 4; ++m)
#pragma unroll
        for (int r = 0; r < 4; ++r) {
          int row = m * 16 + lg * 4 + r;
          sQ[row * 136 + col] = f2bf(accq[m][r]);
          sK[row * 136 + col] = f2bf(acck[m][r]);
          sVT[col * 72 + row] = f2bf(accv[m][r]);   // transposed store
        }
    }
    __syncthreads();

    // ---- attention, 2 heads per pass ----
#pragma unroll 1
    for (int hp = 0; hp < 4; ++hp) {
      const int hh = wave >> 2;        // which head of the pair
      const int head = hp * 2 + hh;
      const int nt = wave & 3;         // key tile
      // scores = Q_h K_h^T * 0.25, causal mask  (K=16 zero-padded to 32)
      {
        f32x4 sc[4];
#pragma unroll
        for (int m = 0; m < 4; ++m) sc[m] = fzero;
        short8 bfr = szero;
        if (lg < 2)
          bfr = *(const short8*)(sK + (nt * 16 + lr) * 136 + head * 16 + lg * 8);
#pragma unroll
        for (int m = 0; m < 4; ++m) {
          short8 afr = szero;
          if (lg < 2)
            afr = *(const short8*)(sQ + (m * 16 + lr) * 136 + head * 16 + lg * 8);
          sc[m] = MFMA(afr, bfr, sc[m]);
        }
        int j = nt * 16 + lr;
#pragma unroll
        for (int m = 0; m < 4; ++m)
#pragma unroll
          for (int r = 0; r < 4; ++r) {
            int qrow = m * 16 + lg * 4 + r;
            float v = sc[m][r] * 0.25f;
            if (j > qrow) v = -1e30f;
            sS[qrow * 132 + hh * 64 + j] = v;
          }
      }
      __syncthreads();
      // softmax rows (8 threads/row: 2 heads x 4 quarters)
      {
        int r = tid >> 3;
        int hh2 = (tid >> 2) & 1;
        int q4 = tid & 3;
        const float* srow = sS + r * 132 + hh2 * 64 + q4 * 16;
        float e16[16];
        float mx = -1e30f;
#pragma unroll
        for (int j = 0; j < 16; ++j) mx = fmaxf(mx, srow[j]);
        mx = fmaxf(mx, __shfl_xor(mx, 1, 64));
        mx = fmaxf(mx, __shfl_xor(mx, 2, 64));
        float ssum = 0.f;
#pragma unroll
        for (int j = 0; j < 16; ++j) { float e = __expf(srow[j] - mx); e16[j] = e; ssum += e; }
        ssum += __shfl_xor(ssum, 1, 64);
        ssum += __shfl_xor(ssum, 2, 64);
        float rinv = 1.f / ssum;
        short* prow = sP + r * 136 + hh2 * 64 + q4 * 16;
#pragma unroll
        for (int j = 0; j < 16; ++j) prow[j] = f2bf(e16[j] * rinv);
      }
      __syncthreads();
      // PV: att tile [16 rows][16 dims] per wave (mt = wave&3)
      {
        int mt = wave & 3;
        f32x4 accp = fzero;
#pragma unroll
        for (int ks = 0; ks < 2; ++ks) {
          short8 a = *(const short8*)(sP + (mt * 16 + lr) * 136 + hh * 64 + ks * 32 + lg * 8);
          short8 bv = *(const short8*)(sVT + (head * 16 + lr) * 72 + ks * 32 + lg * 8);
          accp = MFMA(a, bv, accp);
        }
#pragma unroll
        for (int r = 0; r < 4; ++r)
          sXn[(mt * 16 + lg * 4 + r) * 136 + head * 16 + lr] = f2bf(accp[r]);
      }
      __syncthreads();
    }

    // ---- Wo GEMM + residual: x += att @ Wo^T + bo ----
    {
      const short* wo = wsb + WS_WO + l * 16384;
      f32x4 acc[4];
#pragma unroll
      for (int m = 0; m < 4; ++m) acc[m] = fzero;
#pragma unroll
      for (int ks = 0; ks < 4; ++ks) {
        short8 bfr = *(const short8*)(wo + (ks * 4 + lg) * 1024 + (wave * 16 + lr) * 8);
#pragma unroll
        for (int m = 0; m < 4; ++m) {
          short8 am = *(const short8*)(sXn + (m * 16 + lr) * 136 + ks * 32 + lg * 8);
          acc[m] = MFMA(am, bfr, acc[m]);
        }
      }
      int col = wave * 16 + lr;
      float bov = bo[l * 128 + col];
#pragma unroll
      for (int m = 0; m < 4; ++m)
#pragma unroll
        for (int r = 0; r < 4; ++r)
          sX[(m * 16 + lg * 4 + r) * 132 + col] += acc[m][r] + bov;
    }
    __syncthreads();

    // ---- LN2 ----
    layernorm(sX, sXn, ln2_g + l * 128, ln2_b + l * 128, tid);
    __syncthreads();

    // ---- FF: chunked over hidden dim, GEMM2 accumulator lives in regs ----
    {
      const short* w1 = wsb + WS_W1 + l * 65536;
      const short* w2 = wsb + WS_W2 + l * 65536;
      f32x4 acc2[4];
#pragma unroll
      for (int m = 0; m < 4; ++m) acc2[m] = fzero;
#pragma unroll 1
      for (int f = 0; f < 4; ++f) {
        // GEMM1 chunk + bias + exact gelu -> sP (bf16)
        f32x4 a1[4];
#pragma unroll
        for (int m = 0; m < 4; ++m) a1[m] = fzero;
#pragma unroll
        for (int ks = 0; ks < 4; ++ks) {
          short8 bfr = *(const short8*)(w1 + (ks * 4 + lg) * 4096 +
                                        (f * 128 + wave * 16 + lr) * 8);
#pragma unroll
          for (int m = 0; m < 4; ++m) {
            short8 am = *(const short8*)(sXn + (m * 16 + lr) * 136 + ks * 32 + lg * 8);
            a1[m] = MFMA(am, bfr, a1[m]);
          }
        }
        int col = wave * 16 + lr;
        float b1v = b1[l * 512 + f * 128 + col];
#pragma unroll
        for (int m = 0; m < 4; ++m)
#pragma unroll
          for (int r = 0; r < 4; ++r) {
            float h = a1[m][r] + b1v;
            float gl = 0.5f * h * (1.f + erff(h * 0.70710678118f));
            sP[(m * 16 + lg * 4 + r) * 136 + col] = f2bf(gl);
          }
        __syncthreads();
        // GEMM2 partial: acc2 += h_chunk @ W2_chunk^T
#pragma unroll
        for (int ks = 0; ks < 4; ++ks) {
          short8 bfr = *(const short8*)(w2 + ((f * 16 + ks * 4 + lg) * 128 +
                                              wave * 16 + lr) * 8);
#pragma unroll
          for (int m = 0; m < 4; ++m) {
            short8 am = *(const short8*)(sP + (m * 16 + lr) * 136 + ks * 32 + lg * 8);
            acc2[m] = MFMA(am, bfr, acc2[m]);
          }
        }
        __syncthreads();
      }
      int col = wave * 16 + lr;
      float b2v = b2[l * 128 + col];
#pragma unroll
      for (int m = 0; m < 4; ++m)
#pragma unroll
        for (int r = 0; r < 4; ++r)
          sX[(m * 16 + lg * 4 + r) * 132 + col] += acc2[m][r] + b2v;
    }
    __syncthreads();
  }

  // ---- final LN ----
  layernorm(sX, sXn, lnf_g, lnf_b, tid);
  __syncthreads();

  // ---- logits = xf @ tok_emb^T + lm_b (waves 0..5 cover 96 cols) ----
  if (wave < 6) {
    f32x4 acc[4];
#pragma unroll
    for (int m = 0; m < 4; ++m) acc[m] = fzero;
#pragma unroll
    for (int ks = 0; ks < 4; ++ks) {
      short8 bfr = *(const short8*)(wsb + WS_EMB + (ks * 4 + lg) * 768 +
                                    (wave * 16 + lr) * 8);
#pragma unroll
      for (int m = 0; m < 4; ++m) {
        short8 am = *(const short8*)(sXn + (m * 16 + lr) * 136 + ks * 32 + lg * 8);
        acc[m] = MFMA(am, bfr, acc[m]);
      }
    }
    int col = wave * 16 + lr;
    float lb = lm_b[col];
#pragma unroll
    for (int m = 0; m < 4; ++m)
#pragma unroll
      for (int r = 0; r < 4; ++r) {
        int row = m * 16 + lg * 4 + r;
        float v = acc[m][r] + lb;
        out[((size_t)b * 64 + row) * 96 + col] = v;
        sS[row * 132 + col] = v;
      }
  }
  __syncthreads();

  // ---- per-row cross-entropy -> block partial ----
  {
    int r = tid >> 3, t8 = tid & 7;
    const float* lrow = sS + r * 132 + t8 * 12;
    float mx = -1e30f;
#pragma unroll
    for (int j = 0; j < 12; ++j) mx = fmaxf(mx, lrow[j]);
#pragma unroll
    for (int m = 1; m < 8; m <<= 1) mx = fmaxf(mx, __shfl_xor(mx, m, 64));
    float ssum = 0.f;
#pragma unroll
    for (int j = 0; j < 12; ++j) ssum += __expf(lrow[j] - mx);
#pragma unroll
    for (int m = 1; m < 8; m <<= 1) ssum += __shfl_xor(ssum, m, 64);
    if (t8 == 0) {
      float lse = logf(ssum) + mx;
      int tgt = targets[b * 64 + r];
      sRed[r] = lse - sS[r * 132 + tgt];
    }
  }
  __syncthreads();
  if (wave == 0) {
    float v = sRed[lane];
#pragma unroll
    for (int m = 32; m >= 1; m >>= 1) v += __shfl_xor(v, m, 64);
    if (lane == 0) loss_part[b] = v;
  }
}

// deterministic final reduction: loss = mean over 262144 tokens
__global__ void loss_reduce(const float* __restrict__ loss_part, float* __restrict__ out_loss) {
  __shared__ float red[256];
  int t = threadIdx.x;
  float s = 0.f;
  for (int i = t; i < 4096; i += 256) s += loss_part[i];
  red[t] = s;
  __syncthreads();
  for (int k = 128; k >= 1; k >>= 1) {
    if (t < k) red[t] += red[t + k];
    __syncthreads();
  }
  if (t == 0) out_loss[0] = red[0] * (1.f / 262144.f);
}

extern "C" void kernel_launch(void* const* d_in, const int* in_sizes, int n_in,
                              void* d_out, int out_size, void* d_ws, size_t ws_size,
                              hipStream_t stream) {
  (void)in_sizes; (void)n_in; (void)ws_size;
  const int* idx      = (const int*)d_in[0];
  const int* targets  = (const int*)d_in[1];
  const float* tok_emb = (const float*)d_in[2];
  const float* pos_emb = (const float*)d_in[3];
  const float* Wq = (const float*)d_in[4];
  const float* Wk = (const float*)d_in[5];
  const float* Wv = (const float*)d_in[6];
  const float* Wo = (const float*)d_in[7];
  const float* bo = (const float*)d_in[8];
  const float* ln1_g = (const float*)d_in[9];
  const float* ln1_b = (const float*)d_in[10];
  const float* ln2_g = (const float*)d_in[11];
  const float* ln2_b = (const float*)d_in[12];
  const float* W1 = (const float*)d_in[13];
  const float* b1 = (const float*)d_in[14];
  const float* W2 = (const float*)d_in[15];
  const float* b2 = (const float*)d_in[16];
  const float* lnf_g = (const float*)d_in[17];
  const float* lnf_b = (const float*)d_in[18];
  const float* lm_b = (const float*)d_in[19];

  short* wsb = (short*)d_ws;
  float* loss_part = (float*)((char*)d_ws + (size_t)WS_END * 2);
  float* out = (float*)d_out;

  prep_weights<<<1560, NTHR, 0, stream>>>(tok_emb, Wq, Wk, Wv, Wo, W1, W2, wsb);
  lm_forward<<<4096, NTHR, 0, stream>>>(idx, targets, tok_emb, pos_emb, bo,
                                        ln1_g, ln1_b, ln2_g, ln2_b, b1, b2,
                                        lnf_g, lnf_b, lm_b, wsb, out, loss_part);
  loss_reduce<<<1, 256, 0, stream>>>(loss_part, out + (out_size - 1));
}

// Round 2
// 880.111 us; speedup vs baseline: 1.8174x; 1.8174x over previous
//
#include <hip/hip_runtime.h>
#include <hip/hip_bf16.h>
#include <math.h>

// Problem constants: V=96, D=128, T=64, H=8, HD=16, FF=512, L=4, B=4096
#define NTHR 512

typedef __attribute__((ext_vector_type(8))) short bf16x8;
typedef __attribute__((ext_vector_type(4))) short bf16x4;
typedef __attribute__((ext_vector_type(4))) float f32x4;

#define MFMA32(a, b, c) __builtin_amdgcn_mfma_f32_16x16x32_bf16((a), (b), (c), 0, 0, 0)

#if defined(__has_builtin)
#if __has_builtin(__builtin_amdgcn_mfma_f32_16x16x16bf16_1k)
#define HAVE_MFMA16 1
#endif
#endif
#ifdef HAVE_MFMA16
#define MFMA16(a, b, c) __builtin_amdgcn_mfma_f32_16x16x16bf16_1k((a), (b), (c), 0, 0, 0)
#else
// fallback: raw ISA; conservative s_nops cover VALU->MFMA-src and MFMA-D->VALU hazards
__device__ __forceinline__ f32x4 mfma16_fb(bf16x4 a, bf16x4 b, f32x4 c) {
  asm volatile("s_nop 1\n\tv_mfma_f32_16x16x16_bf16 %0, %1, %2, %0\n\ts_nop 7\n\ts_nop 7"
               : "+v"(c) : "v"(a), "v"(b));
  return c;
}
#define MFMA16(a, b, c) mfma16_fb((a), (b), (c))
#endif

// ---- workspace layout (bf16 element offsets) ----
// weights pre-converted to bf16, swizzled [K/8][N][8]: dst[(k>>3)*N*8 + n*8 + (k&7)] = W[n][k]
#define WS_EMB 0                      // [96][128]
#define WS_WQ  12288                  // 4x[128][128]
#define WS_WK  (WS_WQ + 65536)
#define WS_WV  (WS_WK + 65536)
#define WS_WO  (WS_WV + 65536)
#define WS_W1  (WS_WO + 65536)        // 4x[512][128]
#define WS_W2  (WS_W1 + 262144)       // 4x[128][512]
#define WS_END (WS_W2 + 262144)

__device__ __forceinline__ short f2bf(float f) {
  union { __hip_bfloat16 h; unsigned short s; } u;
  u.h = __float2bfloat16(f);          // HW cvt (v_cvt_pk_bf16_f32 when paired)
  return (short)u.s;
}
__device__ __forceinline__ bf16x4 pk4(f32x4 v) {
  bf16x4 r;
  r[0] = f2bf(v[0]); r[1] = f2bf(v[1]); r[2] = f2bf(v[2]); r[3] = f2bf(v[3]);
  return r;
}
__device__ __forceinline__ float gelu_tanh(float x) {
  float y = x * (0.7978845608f + 0.0356774081f * x * x);
  float sg = __builtin_amdgcn_rcpf(1.f + __expf(-2.f * y));
  return x * sg;
}

__global__ void prep_weights(const float* __restrict__ tok_emb,
                             const float* __restrict__ Wq, const float* __restrict__ Wk,
                             const float* __restrict__ Wv, const float* __restrict__ Wo,
                             const float* __restrict__ W1, const float* __restrict__ W2,
                             short* __restrict__ wsb) {
  int i = blockIdx.x * NTHR + threadIdx.x;
  if (i < 12288) {                       // tok_emb [96][128]
    int n = i >> 7, k = i & 127;
    wsb[WS_EMB + (k >> 3) * 768 + n * 8 + (k & 7)] = f2bf(tok_emb[i]);
    return;
  }
  i -= 12288;
  if (i < 262144) {                      // Wq,Wk,Wv,Wo: [4][128][128] each
    int tensor = i >> 16;
    int rem = i & 65535;
    int l = rem >> 14;
    int w = rem & 16383;
    int n = w >> 7, k = w & 127;
    const float* src = tensor == 0 ? Wq : tensor == 1 ? Wk : tensor == 2 ? Wv : Wo;
    wsb[WS_WQ + tensor * 65536 + l * 16384 + (k >> 3) * 1024 + n * 8 + (k & 7)] =
        f2bf(src[rem]);
    return;
  }
  i -= 262144;
  if (i < 262144) {                      // W1 [4][512][128]
    int l = i >> 16;
    int w = i & 65535;
    int n = w >> 7, k = w & 127;
    wsb[WS_W1 + l * 65536 + (k >> 3) * 4096 + n * 8 + (k & 7)] = f2bf(W1[i]);
    return;
  }
  i -= 262144;
  if (i < 262144) {                      // W2 [4][128][512]
    int l = i >> 16;
    int w = i & 65535;
    int n = w >> 9, k = w & 511;
    wsb[WS_W2 + l * 65536 + (k >> 3) * 1024 + n * 8 + (k & 7)] = f2bf(W2[i]);
  }
}

// vectorized LN: 8 threads/row, f32x4 loads, packed bf16x4 stores
__device__ __forceinline__ void layernorm(const float* __restrict__ sXl,
                                          short* __restrict__ dstl,
                                          const float* __restrict__ g,
                                          const float* __restrict__ be, int tid) {
  int r = tid >> 3, t8 = tid & 7;
  const f32x4* row = (const f32x4*)(sXl + r * 132 + t8 * 16);
  f32x4 v[4];
  float s = 0.f, s2 = 0.f;
#pragma unroll
  for (int j = 0; j < 4; ++j) {
    v[j] = row[j];
#pragma unroll
    for (int c = 0; c < 4; ++c) { s += v[j][c]; s2 += v[j][c] * v[j][c]; }
  }
  s  += __shfl_xor(s, 1, 64);  s  += __shfl_xor(s, 2, 64);  s  += __shfl_xor(s, 4, 64);
  s2 += __shfl_xor(s2, 1, 64); s2 += __shfl_xor(s2, 2, 64); s2 += __shfl_xor(s2, 4, 64);
  float mean = s * 0.0078125f;
  float rs = rsqrtf(s2 * 0.0078125f - mean * mean + 1e-5f);
  const f32x4* gp = (const f32x4*)(g + t8 * 16);
  const f32x4* bp = (const f32x4*)(be + t8 * 16);
  bf16x4* dp = (bf16x4*)(dstl + r * 136 + t8 * 16);
#pragma unroll
  for (int j = 0; j < 4; ++j) {
    f32x4 gg = gp[j], bb = bp[j], o;
#pragma unroll
    for (int c = 0; c < 4; ++c) o[c] = (v[j][c] - mean) * rs * gg[c] + bb[c];
    dp[j] = pk4(o);
  }
}

// One block per sequence, 8 waves.
// MFMA 16x16x32 layouts (HW-verified): A[l&15][(l>>4)*8+i], B[(l>>4)*8+i][l&15],
//   D: row=(l>>4)*4+reg, col=l&15.  16x16x16: same with 4 k per lane.
// GEMMs run "transposed" (A=weight, B=X^T, D=out^T) so epilogues pack 4 consecutive
// outputs per lane (b64/b128 stores). Attention: wave=head, softmax in registers,
// P^T feeds PV's 16x16x16 B-fragment directly from the score accumulators.
__global__ __launch_bounds__(512, 2)
void lm_forward(const int* __restrict__ idx, const int* __restrict__ targets,
                const float* __restrict__ tok_emb, const float* __restrict__ pos_emb,
                const float* __restrict__ bo, const float* __restrict__ ln1_g,
                const float* __restrict__ ln1_b, const float* __restrict__ ln2_g,
                const float* __restrict__ ln2_b, const float* __restrict__ b1,
                const float* __restrict__ b2, const float* __restrict__ lnf_g,
                const float* __restrict__ lnf_b, const float* __restrict__ lm_b,
                const short* __restrict__ wsb, float* __restrict__ out,
                float* __restrict__ loss_part) {
  __shared__ __align__(16) char smem[118016];
  float* sX  = (float*)smem;                 // [64][132] f32 residual
  short* sXn = (short*)(smem + 33792);       // [64][136] bf16 (LN out / att out)
  char*  Rg  = smem + 51200;                 // overlapped region
  short* sQ  = (short*)Rg;                   // [64][136] bf16
  short* sK  = (short*)(Rg + 17408);         // [64][136] bf16
  short* sVT = (short*)(Rg + 34816);         // [128][72] bf16 (V^T)
  short* sH  = (short*)Rg;                   // [64][520] bf16 (FF hidden)
  float* sL  = (float*)Rg;                   // [64][100] f32 (logits)
  float* sRed = (float*)(smem + 117760);

  const int b = blockIdx.x;
  const int tid = threadIdx.x;
  const int wave = tid >> 6;
  const int lane = tid & 63;
  const int lr = lane & 15;
  const int lg = lane >> 4;
  const f32x4 fz = {0.f, 0.f, 0.f, 0.f};

  // ---- embedding ----
#pragma unroll
  for (int k = 0; k < 4; ++k) {
    int e = (tid + k * 512) * 4;
    int t = e >> 7, d = e & 127;
    f32x4 te = *(const f32x4*)(tok_emb + idx[b * 64 + t] * 128 + d);
    f32x4 pe = *(const f32x4*)(pos_emb + e);
    *(f32x4*)(sX + t * 132 + d) = te + pe;
  }
  __syncthreads();

#pragma unroll 1
  for (int l = 0; l < 4; ++l) {
    layernorm(sX, sXn, ln1_g + l * 128, ln1_b + l * 128, tid);
    __syncthreads();

    // ---- QKV (Q^T,K^T transposed-orientation; V normal) ----
    {
      const short* wq = wsb + WS_WQ + l * 16384;
      const short* wk = wsb + WS_WK + l * 16384;
      const short* wv = wsb + WS_WV + l * 16384;
      f32x4 aq[4], ak[4], av[4];
#pragma unroll
      for (int n = 0; n < 4; ++n) { aq[n] = fz; ak[n] = fz; av[n] = fz; }
#pragma unroll
      for (int ks = 0; ks < 4; ++ks) {
        bf16x8 xf[4];
#pragma unroll
        for (int n = 0; n < 4; ++n)
          xf[n] = *(const bf16x8*)(sXn + (n * 16 + lr) * 136 + ks * 32 + lg * 8);
        int wo_ = (ks * 4 + lg) * 1024 + (wave * 16 + lr) * 8;
        bf16x8 qf = *(const bf16x8*)(wq + wo_);
        bf16x8 kf = *(const bf16x8*)(wk + wo_);
        bf16x8 vf = *(const bf16x8*)(wv + wo_);
#pragma unroll
        for (int n = 0; n < 4; ++n) {
          aq[n] = MFMA32(qf, xf[n], aq[n]);
          ak[n] = MFMA32(kf, xf[n], ak[n]);
          av[n] = MFMA32(xf[n], vf, av[n]);
        }
      }
#pragma unroll
      for (int n = 0; n < 4; ++n) {
        *(bf16x4*)(sQ + (n * 16 + lr) * 136 + wave * 16 + lg * 4) = pk4(aq[n]);
        *(bf16x4*)(sK + (n * 16 + lr) * 136 + wave * 16 + lg * 4) = pk4(ak[n]);
        *(bf16x4*)(sVT + (wave * 16 + lr) * 72 + n * 16 + lg * 4) = pk4(av[n]);
      }
    }
    __syncthreads();

    // ---- attention: wave = head, fully in-register softmax ----
    {
      const int h = wave;
      f32x4 sc[4][4];
#pragma unroll
      for (int m = 0; m < 4; ++m)
#pragma unroll
        for (int n = 0; n < 4; ++n) sc[m][n] = fz;
      bf16x4 kf[4], qf[4];
#pragma unroll
      for (int m = 0; m < 4; ++m)
        kf[m] = *(const bf16x4*)(sK + (m * 16 + lr) * 136 + h * 16 + lg * 4);
#pragma unroll
      for (int n = 0; n < 4; ++n)
        qf[n] = *(const bf16x4*)(sQ + (n * 16 + lr) * 136 + h * 16 + lg * 4);
#pragma unroll
      for (int m = 0; m < 4; ++m)      // S^T[key][query] = K Q^T
#pragma unroll
        for (int n = 0; n < 4; ++n) sc[m][n] = MFMA16(kf[m], qf[n], sc[m][n]);

      bf16x4 pf[4][4];
#pragma unroll
      for (int n = 0; n < 4; ++n) {
        int qq = n * 16 + lr;          // query index (column)
        float mx = -1e30f;
#pragma unroll
        for (int m = 0; m < 4; ++m)
#pragma unroll
          for (int r = 0; r < 4; ++r) {
            int kk = m * 16 + lg * 4 + r;       // key index (row)
            float s = sc[m][n][r];
            if (kk > qq) s = -1e30f;            // causal mask
            sc[m][n][r] = s;
            mx = fmaxf(mx, s);
          }
        mx = fmaxf(mx, __shfl_xor(mx, 16, 64));
        mx = fmaxf(mx, __shfl_xor(mx, 32, 64));
        float sum = 0.f;
#pragma unroll
        for (int m = 0; m < 4; ++m)
#pragma unroll
          for (int r = 0; r < 4; ++r) {
            float p = __expf((sc[m][n][r] - mx) * 0.25f);  // scale folded in
            sc[m][n][r] = p;
            sum += p;
          }
        sum += __shfl_xor(sum, 16, 64);
        sum += __shfl_xor(sum, 32, 64);
        float rinv = __builtin_amdgcn_rcpf(sum);
#pragma unroll
        for (int m = 0; m < 4; ++m) {
          f32x4 pv;
#pragma unroll
          for (int r = 0; r < 4; ++r) pv[r] = sc[m][n][r] * rinv;
          pf[m][n] = pk4(pv);          // P^T B-fragment, lane-local!
        }
      }
      // PV: att^T = V^T P^T
      f32x4 ao[4];
#pragma unroll
      for (int n = 0; n < 4; ++n) ao[n] = fz;
#pragma unroll
      for (int m = 0; m < 4; ++m) {
        bf16x4 vf = *(const bf16x4*)(sVT + (h * 16 + lr) * 72 + m * 16 + lg * 4);
#pragma unroll
        for (int n = 0; n < 4; ++n) ao[n] = MFMA16(vf, pf[m][n], ao[n]);
      }
#pragma unroll
      for (int n = 0; n < 4; ++n)
        *(bf16x4*)(sXn + (n * 16 + lr) * 136 + h * 16 + lg * 4) = pk4(ao[n]);
    }
    __syncthreads();

    // ---- Wo + residual ----
    {
      const short* wo = wsb + WS_WO + l * 16384;
      f32x4 ac[4];
#pragma unroll
      for (int n = 0; n < 4; ++n) ac[n] = fz;
#pragma unroll
      for (int ks = 0; ks < 4; ++ks) {
        bf16x8 wf = *(const bf16x8*)(wo + (ks * 4 + lg) * 1024 + (wave * 16 + lr) * 8);
#pragma unroll
        for (int n = 0; n < 4; ++n) {
          bf16x8 bfg = *(const bf16x8*)(sXn + (n * 16 + lr) * 136 + ks * 32 + lg * 8);
          ac[n] = MFMA32(wf, bfg, ac[n]);
        }
      }
      f32x4 bo4 = *(const f32x4*)(bo + l * 128 + wave * 16 + lg * 4);
#pragma unroll
      for (int n = 0; n < 4; ++n) {
        f32x4* px = (f32x4*)(sX + (n * 16 + lr) * 132 + wave * 16 + lg * 4);
        *px = *px + ac[n] + bo4;
      }
    }
    __syncthreads();

    layernorm(sX, sXn, ln2_g + l * 128, ln2_b + l * 128, tid);
    __syncthreads();

    // ---- FF (unchunked hidden, 1 barrier pair) ----
    {
      const short* w1 = wsb + WS_W1 + l * 65536;
      const short* w2 = wsb + WS_W2 + l * 65536;
      f32x4 a1[4][4];
#pragma unroll
      for (int g = 0; g < 4; ++g)
#pragma unroll
        for (int n = 0; n < 4; ++n) a1[g][n] = fz;
#pragma unroll
      for (int ks = 0; ks < 4; ++ks) {
        bf16x8 xf[4];
#pragma unroll
        for (int n = 0; n < 4; ++n)
          xf[n] = *(const bf16x8*)(sXn + (n * 16 + lr) * 136 + ks * 32 + lg * 8);
#pragma unroll
        for (int g = 0; g < 4; ++g) {
          bf16x8 wf = *(const bf16x8*)(w1 + (ks * 4 + lg) * 4096 +
                                       (wave * 64 + g * 16 + lr) * 8);
#pragma unroll
          for (int n = 0; n < 4; ++n) a1[g][n] = MFMA32(wf, xf[n], a1[g][n]);
        }
      }
#pragma unroll
      for (int g = 0; g < 4; ++g) {
        f32x4 b1v = *(const f32x4*)(b1 + l * 512 + wave * 64 + g * 16 + lg * 4);
#pragma unroll
        for (int n = 0; n < 4; ++n) {
          f32x4 hv;
#pragma unroll
          for (int r = 0; r < 4; ++r) hv[r] = gelu_tanh(a1[g][n][r] + b1v[r]);
          *(bf16x4*)(sH + (n * 16 + lr) * 520 + wave * 64 + g * 16 + lg * 4) = pk4(hv);
        }
      }
      __syncthreads();
      f32x4 a2[4];
#pragma unroll
      for (int n = 0; n < 4; ++n) a2[n] = fz;
#pragma unroll
      for (int ks = 0; ks < 16; ++ks) {
        bf16x8 wf = *(const bf16x8*)(w2 + (ks * 4 + lg) * 1024 + (wave * 16 + lr) * 8);
#pragma unroll
        for (int n = 0; n < 4; ++n) {
          bf16x8 hf = *(const bf16x8*)(sH + (n * 16 + lr) * 520 + ks * 32 + lg * 8);
          a2[n] = MFMA32(wf, hf, a2[n]);
        }
      }
      f32x4 b2v = *(const f32x4*)(b2 + l * 128 + wave * 16 + lg * 4);
#pragma unroll
      for (int n = 0; n < 4; ++n) {
        f32x4* px = (f32x4*)(sX + (n * 16 + lr) * 132 + wave * 16 + lg * 4);
        *px = *px + a2[n] + b2v;
      }
    }
    __syncthreads();
  }

  // ---- final LN ----
  layernorm(sX, sXn, lnf_g, lnf_b, tid);
  __syncthreads();

  // ---- logits (transposed orientation, float4 global stores) ----
  if (wave < 6) {
    f32x4 al[4];
#pragma unroll
    for (int n = 0; n < 4; ++n) al[n] = fz;
#pragma unroll
    for (int ks = 0; ks < 4; ++ks) {
      bf16x8 ef = *(const bf16x8*)(wsb + WS_EMB + (ks * 4 + lg) * 768 +
                                   (wave * 16 + lr) * 8);
#pragma unroll
      for (int n = 0; n < 4; ++n) {
        bf16x8 xf = *(const bf16x8*)(sXn + (n * 16 + lr) * 136 + ks * 32 + lg * 8);
        al[n] = MFMA32(ef, xf, al[n]);
      }
    }
    f32x4 lb = *(const f32x4*)(lm_b + wave * 16 + lg * 4);
#pragma unroll
    for (int n = 0; n < 4; ++n) {
      f32x4 v = al[n] + lb;
      int token = n * 16 + lr;
      *(f32x4*)(out + ((size_t)b * 64 + token) * 96 + wave * 16 + lg * 4) = v;
      *(f32x4*)(sL + token * 100 + wave * 16 + lg * 4) = v;
    }
  }
  __syncthreads();

  // ---- per-row cross-entropy ----
  {
    int r = tid >> 3, t8 = tid & 7;
    const float* lrow = sL + r * 100 + t8 * 12;
    float mx = -1e30f;
#pragma unroll
    for (int j = 0; j < 12; ++j) mx = fmaxf(mx, lrow[j]);
    mx = fmaxf(mx, __shfl_xor(mx, 1, 64));
    mx = fmaxf(mx, __shfl_xor(mx, 2, 64));
    mx = fmaxf(mx, __shfl_xor(mx, 4, 64));
    float sum = 0.f;
#pragma unroll
    for (int j = 0; j < 12; ++j) sum += __expf(lrow[j] - mx);
    sum += __shfl_xor(sum, 1, 64);
    sum += __shfl_xor(sum, 2, 64);
    sum += __shfl_xor(sum, 4, 64);
    if (t8 == 0) {
      float lse = logf(sum) + mx;
      sRed[r] = lse - sL[r * 100 + targets[b * 64 + r]];
    }
  }
  __syncthreads();
  if (wave == 0) {
    float v = sRed[lane];
#pragma unroll
    for (int m = 32; m >= 1; m >>= 1) v += __shfl_xor(v, m, 64);
    if (lane == 0) loss_part[b] = v;
  }
}

__global__ void loss_reduce(const float* __restrict__ loss_part, float* __restrict__ out_loss) {
  __shared__ float red[256];
  int t = threadIdx.x;
  float s = 0.f;
  for (int i = t; i < 4096; i += 256) s += loss_part[i];
  red[t] = s;
  __syncthreads();
  for (int k = 128; k >= 1; k >>= 1) {
    if (t < k) red[t] += red[t + k];
    __syncthreads();
  }
  if (t == 0) out_loss[0] = red[0] * (1.f / 262144.f);
}

extern "C" void kernel_launch(void* const* d_in, const int* in_sizes, int n_in,
                              void* d_out, int out_size, void* d_ws, size_t ws_size,
                              hipStream_t stream) {
  (void)in_sizes; (void)n_in; (void)ws_size;
  const int* idx      = (const int*)d_in[0];
  const int* targets  = (const int*)d_in[1];
  const float* tok_emb = (const float*)d_in[2];
  const float* pos_emb = (const float*)d_in[3];
  const float* Wq = (const float*)d_in[4];
  const float* Wk = (const float*)d_in[5];
  const float* Wv = (const float*)d_in[6];
  const float* Wo = (const float*)d_in[7];
  const float* bo = (const float*)d_in[8];
  const float* ln1_g = (const float*)d_in[9];
  const float* ln1_b = (const float*)d_in[10];
  const float* ln2_g = (const float*)d_in[11];
  const float* ln2_b = (const float*)d_in[12];
  const float* W1 = (const float*)d_in[13];
  const float* b1 = (const float*)d_in[14];
  const float* W2 = (const float*)d_in[15];
  const float* b2 = (const float*)d_in[16];
  const float* lnf_g = (const float*)d_in[17];
  const float* lnf_b = (const float*)d_in[18];
  const float* lm_b = (const float*)d_in[19];

  short* wsb = (short*)d_ws;
  float* loss_part = (float*)((char*)d_ws + (size_t)WS_END * 2);
  float* out = (float*)d_out;

  prep_weights<<<1560, NTHR, 0, stream>>>(tok_emb, Wq, Wk, Wv, Wo, W1, W2, wsb);
  lm_forward<<<4096, NTHR, 0, stream>>>(idx, targets, tok_emb, pos_emb, bo,
                                        ln1_g, ln1_b, ln2_g, ln2_b, b1, b2,
                                        lnf_g, lnf_b, lm_b, wsb, out, loss_part);
  loss_reduce<<<1, 256, 0, stream>>>(loss_part, out + (out_size - 1));
}